// Round 23
// baseline (80.367 us; speedup 1.0000x reference)
//
#include <hip/hip_runtime.h>

#define BB 8
#define CC 256
#define HH 96
#define WW 96
#define HWW (HH*WW)
#define NLOC 256        // local prototypes (MFMA path)
#define PPAD 257        // + global prototype
#define THRESH 0.95f
#define NORM_EPS 1e-4f

typedef __attribute__((ext_vector_type(8))) _Float16 f16x8;
typedef __attribute__((ext_vector_type(16))) float f32x16;

union H16 { _Float16 f; unsigned short u; };

// ---- fused kernel 0+1: mask pooling (8 blocks) + feature pooling (2048) ----
__global__ void k01(const float* __restrict__ sup_fts,
                    const float* __restrict__ sup_mask,
                    const float* __restrict__ true_bg,
                    float* __restrict__ protos,
                    float* __restrict__ validf,
                    float* __restrict__ masksum) {
    __shared__ float red[256];
    int blk = blockIdx.x;
    int t = threadIdx.x;
    if (blk < BB * CC) {
        int b = blk >> 8, c = blk & 255;
        int gy = t >> 4, gx = t & 15;
        const float* fb = sup_fts + ((size_t)b * CC + c) * HWW;
        const float* mb = sup_mask + (size_t)b * HWW;
        int base = gy * 6 * WW + gx * 6;
        float fs = 0.f, fm = 0.f;
        for (int r = 0; r < 6; ++r) {
            const float* rowf = fb + base + r * WW;
            const float* rowm = mb + base + r * WW;
#pragma unroll
            for (int h = 0; h < 3; ++h) {
                float2 v  = *(const float2*)(rowf + 2 * h);
                float2 mk = *(const float2*)(rowm + 2 * h);
                fs += v.x + v.y;
                fm = fmaf(v.x, mk.x, fm);
                fm = fmaf(v.y, mk.y, fm);
            }
        }
        protos[((size_t)b * PPAD + t) * CC + c] = fs * (1.f / 36.f);
        red[t] = fm;
        __syncthreads();
        for (int off = 128; off > 0; off >>= 1) {
            if (t < off) red[t] += red[t + off];
            __syncthreads();
        }
        if (t == 0) protos[((size_t)b * PPAD + 256) * CC + c] = red[0];
    } else {
        int b = blk - BB * CC;
        int gy = t >> 4, gx = t & 15;
        const float* mb = sup_mask + (size_t)b * HWW;
        const float* gb = true_bg  + (size_t)b * HWW;
        int base = gy * 6 * WW + gx * 6;
        float ms = 0.f, bs = 0.f;
        for (int r = 0; r < 6; ++r) {
            const float* rowm = mb + base + r * WW;
            const float* rowg = gb + base + r * WW;
#pragma unroll
            for (int h = 0; h < 3; ++h) {
                float2 mk = *(const float2*)(rowm + 2 * h);
                float2 bg2 = *(const float2*)(rowg + 2 * h);
                ms += mk.x + mk.y;
                bs += bg2.x + bg2.y;
            }
        }
        float mmean = ms * (1.f / 36.f);
        float bmean = bs * (1.f / 36.f);
        validf[b * PPAD + t] = (mmean > THRESH && bmean < 0.5f) ? 1.f : 0.f;
        if (t == 0) validf[b * PPAD + 256] = 1.f;
        red[t] = ms;
        __syncthreads();
        for (int off = 128; off > 0; off >>= 1) {
            if (t < off) red[t] += red[t + off];
            __syncthreads();
        }
        if (t == 0) masksum[b] = red[0];
    }
}

// ------- kernel 2: finish gproto + normalize + emit fp16 proto image --------
// Pimg layout (fp16): [B][16 kstep][2 khalf][8 tile][32 col][8 e]
__global__ void k2_norm(float* __restrict__ protos,
                        const float* __restrict__ masksum,
                        unsigned short* __restrict__ Pimg) {
    int bp = blockIdx.x;
    int b = bp / PPAD;
    int p = bp - b * PPAD;
    int t = threadIdx.x;            // channel
    float v = protos[((size_t)b * PPAD + p) * CC + t];
    if (p == 256) v = v / (masksum[b] + 1e-5f);
    __shared__ float red[256];
    red[t] = v * v;
    __syncthreads();
    for (int off = 128; off > 0; off >>= 1) {
        if (t < off) red[t] += red[t + off];
        __syncthreads();
    }
    float norm = sqrtf(red[0]);
    float vn = v / fmaxf(norm, NORM_EPS);
    protos[((size_t)b * PPAD + p) * CC + t] = vn;
    if (p < NLOC) {
        H16 h; h.f = (_Float16)vn;            // RNE, err 2^-11
        int kstep = t >> 4, khalf = (t >> 3) & 1, e = t & 7;
        int tile = p >> 5, col = p & 31;
        size_t idx = ((((size_t)b * 16 + kstep) * 2 + khalf) * 8 + tile) * 256
                     + col * 8 + e;
        Pimg[idx] = h.u;
    }
}

// ---------------- kernel 3: MFMA dists + masked softmax + weighted sum ------
// The 20-round invariant: k3 dur ~= FETCH/750GB/s — HBM-fetch-duty-bound
// (per block: one ~900cyc staging burst, then ~4k cyc compute with ZERO
// fetch in flight). Fix: TILE-LEVEL double-buffered global_load_lds —
// block owns 2 tiles; stage(i+1) is issued BEFORE marathon(i) (zero VGPR,
// can't spill: the r14 killer), completes under marathon+epilogue, and the
// epilogue's existing __syncthreads doubles as its free drain.
// Marathon (fused convert, r22) + epilogue byte-identical to r22
// (refcheck'd absmax 1.2207e-4).
__global__ __launch_bounds__(256, 2)
void k3_mfma(const float* __restrict__ qry,
             const unsigned short* __restrict__ Pimg,
             const float* __restrict__ protos_n,
             const float* __restrict__ validf,
             float* __restrict__ out) {
    __shared__ alignas(16) float Qraw[2][256 * 32];   // dbuf, 2 x 32 KB
    __shared__ float gpl[256];                        // gproto_n
    __shared__ float rn_s[32], gd_s[32];
    __shared__ float S_l[4][32], N_l[4][32];

    int bid = blockIdx.x;
    int b = bid & 7;                  // batch <-> XCD affinity
    int tgrp = bid >> 3;              // 0..143
    int px0 = tgrp * 64;              // 2 tiles: px0, px0+32
    int t = threadIdx.x;              // 0..255
    int l = t & 63;
    int w = t >> 6;                   // wave 0..3
    int col = l & 31;                 // proto-col / pixel index in frag space
    int h = l >> 5;                   // k-half lane bit

    const float* qbase = qry + (size_t)b * CC * HWW;
    const float* gp = protos_n + ((size_t)b * PPAD + 256) * CC;
    const unsigned short* Pb = Pimg + (size_t)b * 65536;

    float vf0 = validf[b * PPAD + w * 64 + col];
    float vf1 = validf[b * PPAD + w * 64 + 32 + col];

#define STAGE(PX0, BUF)                                                       \
    {                                                                         \
        char* dstbase = (char*)&Qraw[BUF][0] + w * 1024;                      \
        _Pragma("unroll")                                                     \
        for (int i = 0; i < 8; ++i) {                                         \
            int F = i * 256 + t;                  /* cell = ch*8 + pxq */     \
            int ch = F >> 3, pxq = F & 7;                                     \
            __builtin_amdgcn_global_load_lds(                                 \
                (const void*)(qbase + (size_t)ch * HWW + (PX0) + pxq * 4),    \
                (void*)(dstbase + i * 4096), 16, 0, 0);                       \
        }                                                                     \
    }

#define LOADB(KS, BUF)                                                        \
    {                                                                         \
        _Pragma("unroll")                                                     \
        for (int ti = 0; ti < 2; ++ti)                                        \
            Bf[BUF][ti] = *(const f16x8*)(Pb +                                \
                ((((size_t)(KS) * 2 + h) * 8 + (w * 2 + ti)) * 32 + col) * 8);\
    }

    // ---- prologue: gproto -> LDS + stage tile 0 ----
    gpl[t] = gp[t];
    STAGE(px0, 0);
    __syncthreads();                  // drains stage(0) — the only exposed wait

#pragma unroll
    for (int tix2 = 0; tix2 < 2; ++tix2) {
        // issue next tile's stage BEFORE this tile's compute (fetch overlap)
        if (tix2 == 0) STAGE(px0 + 32, 1);

        // ---- marathon (r22): 16 ks x {8 raw ds_read + cvt, 2 MFMA} ----
        f32x16 acc[2];
#pragma unroll
        for (int i = 0; i < 16; ++i) { acc[0][i] = 0.f; acc[1][i] = 0.f; }
        f16x8 Bf[2][2];
        float nrm = 0.f, gac = 0.f;
        const float* Qb = &Qraw[tix2][0];

        LOADB(0, 0);
        LOADB(1, 1);
#pragma unroll
        for (int ks = 0; ks < 16; ++ks) {
            int c0 = ks * 16 + h * 8;             // this lane's 8 channels
            float qv[8];
#pragma unroll
            for (int i = 0; i < 8; ++i) qv[i] = Qb[(c0 + i) * 32 + col];
            unsigned int us[8];
#pragma unroll
            for (int i = 0; i < 8; ++i) {
                H16 x; x.f = (_Float16)qv[i];     // RNE (r13 numerics)
                us[i] = x.u;
                nrm = fmaf(qv[i], qv[i], nrm);
                gac = fmaf(qv[i], gpl[c0 + i], gac);
            }
            union { f16x8 v; unsigned int u[4]; } QA;
            QA.u[0] = us[0] | (us[1] << 16); QA.u[1] = us[2] | (us[3] << 16);
            QA.u[2] = us[4] | (us[5] << 16); QA.u[3] = us[6] | (us[7] << 16);
#pragma unroll
            for (int ti = 0; ti < 2; ++ti)
                acc[ti] = __builtin_amdgcn_mfma_f32_32x32x16_f16(QA.v, Bf[ks & 1][ti], acc[ti], 0, 0, 0);
            if (ks + 2 < 16) LOADB(ks + 2, ks & 1);
        }

        // ---- finish |q|^2 and gproto-dot: h-pair merge; px = col ----
        nrm += __shfl_xor(nrm, 32);
        gac += __shfl_xor(gac, 32);
        if (w == 0 && l < 32) {
            float rn = 1.f / fmaxf(sqrtf(nrm), NORM_EPS);
            rn_s[l] = rn;
            gd_s[l] = gac * rn;
        }
        __syncthreads();              // rn_s/gd_s visible (also drains stage(1))

        // ---- softmax epilogue (r13-verified D-map) ----
#pragma unroll
        for (int r = 0; r < 16; ++r) {
            int row = (r & 3) + 8 * (r >> 2) + 4 * h;
            float rnv = rn_s[row];
            float d0 = acc[0][r] * rnv;
            float d1 = acc[1][r] * rnv;
            float l0 = (vf0 != 0.f) ? d0 : -1e30f;
            float l1 = (vf1 != 0.f) ? d1 : -1e30f;
            float e0 = __expf(l0 - 1.1f);         // masked -> exactly 0
            float e1 = __expf(l1 - 1.1f);
            float s = e0 + e1;
            float nn = fmaf(e0, l0, e1 * l1);
#pragma unroll
            for (int m = 1; m < 32; m <<= 1) {
                s  += __shfl_xor(s, m);
                nn += __shfl_xor(nn, m);
            }
            if (col == 0) { S_l[w][row] = s; N_l[w][row] = nn; }
        }
        __syncthreads();

        if (t < 32) {
            float gdv = gd_s[t];
            float eg = __expf(gdv - 1.1f);        // global proto, exactly once
            float S = eg, N = eg * gdv;
#pragma unroll
            for (int i = 0; i < 4; ++i) { S += S_l[i][t]; N += N_l[i][t]; }
            out[(size_t)b * HWW + px0 + tix2 * 32 + t] = N / S;
        }
        if (tix2 == 0) __syncthreads();   // S_l/rn_s reusable for tile 1
    }
#undef STAGE
#undef LOADB
}

extern "C" void kernel_launch(void* const* d_in, const int* in_sizes, int n_in,
                              void* d_out, int out_size, void* d_ws, size_t ws_size,
                              hipStream_t stream) {
    const float* qry = (const float*)d_in[0];
    const float* sup = (const float*)d_in[1];
    const float* msk = (const float*)d_in[2];
    const float* bg  = (const float*)d_in[3];
    float* out = (float*)d_out;

    float* ws = (float*)d_ws;
    float* protos  = ws;                                   // [B][257][256] f32
    float* validf  = protos + (size_t)BB * PPAD * CC;      // [B][257]
    float* masksum = validf + (size_t)BB * PPAD;           // [B]
    unsigned short* Pimg = (unsigned short*)(masksum + BB); // [B][16][2][8][32][8] fp16

    hipLaunchKernelGGL(k01, dim3(BB * CC + BB), dim3(256), 0, stream,
                       sup, msk, bg, protos, validf, masksum);
    hipLaunchKernelGGL(k2_norm, dim3(BB * PPAD), dim3(256), 0, stream, protos, masksum, Pimg);
    hipLaunchKernelGGL(k3_mfma, dim3(BB * (HWW / 64)), dim3(256), 0, stream,
                       qry, Pimg, protos, validf, out);
}